// Round 5
// baseline (226.184 us; speedup 1.0000x reference)
//
#include <hip/hip_runtime.h>

// Sizes fixed by the reference.
#define BB 4
#define SS 4096
#define DM 1024
#define HID 64
#define KTOP 204
static constexpr size_t PATTERN_N = (size_t)BB * SS * SS;  // 67108864

typedef float f4 __attribute__((ext_vector_type(4)));

// ---------------------------------------------------------------------------
// K1: scores[b,s] = relu(emb[b,s,:] @ W1 + b1) @ W2 + b2
// 512 blocks x 256 threads. lane = token (64 tokens/block); wave = 256-wide
// d-slice. Per k: ONE ds_read_b32 gives every lane its e[token][k] (pad-65
// transpose, 2-way conflicts = free); W1 row k is wave-uniform -> s_load
// (K$-resident, all waves lockstep); 64 v_fmac with SGPR w-operand into
// acc[64]. No broadcasts, no cross-lane. VALU floor = 27.3 us.
// ---------------------------------------------------------------------------
__global__ __launch_bounds__(256, 2) void k1_scores(
    const float* __restrict__ emb, const float* __restrict__ W1,
    const float* __restrict__ b1, const float* __restrict__ W2,
    const float* __restrict__ b2, float* __restrict__ scores) {
  __shared__ __align__(16) float ldsT[4][64 * 65];  // per-wave transpose buf
  __shared__ float lds3[4][64];
  const int tid = threadIdx.x;
  const int lane = tid & 63;   // token within block
  const int wv = tid >> 6;     // d-slice id
  const int tok0 = blockIdx.x * 64;
  const int dsl0 = wv * 256;
  const int c4 = lane & 15;    // f4-column within 64-d chunk
  const int rbase = lane >> 4; // row sub-offset

  float acc[64];
#pragma unroll
  for (int h = 0; h < 64; ++h) acc[h] = 0.f;

  float* __restrict__ Tw = &ldsT[wv][0];

#pragma unroll 1
  for (int ch = 0; ch < 4; ++ch) {
    const int d0 = dsl0 + ch * 64;
    // stage 64 tok x 64 d, transposed [d][tok] with stride 65 (wave-local)
#pragma unroll
    for (int i = 0; i < 16; ++i) {
      const int r = i * 4 + rbase;
      f4 v = *reinterpret_cast<const f4*>(
          &emb[((size_t)tok0 + r) * DM + d0 + c4 * 4]);
      Tw[(c4 * 4 + 0) * 65 + r] = v.x;
      Tw[(c4 * 4 + 1) * 65 + r] = v.y;
      Tw[(c4 * 4 + 2) * 65 + r] = v.z;
      Tw[(c4 * 4 + 3) * 65 + r] = v.w;
    }
    // wave-local write->read ordering (no cross-wave sharing, no barrier)
    asm volatile("s_waitcnt lgkmcnt(0)" ::: "memory");
#pragma unroll 2
    for (int k = 0; k < 64; ++k) {
      const float ev = Tw[k * 65 + lane];
      const float* __restrict__ wk = W1 + (size_t)(d0 + k) * HID;
#pragma unroll
      for (int h = 0; h < 64; ++h) acc[h] = fmaf(ev, wk[h], acc[h]);
    }
  }

  // reuse own staging region as [h][tok] partial buffer (4096 <= 64*65)
#pragma unroll
  for (int h = 0; h < 64; ++h) Tw[h * 64 + lane] = acc[h];
  __syncthreads();

  // combine: wave wv handles h in [wv*16, wv*16+16), lane = token
  float p = 0.f;
#pragma unroll
  for (int j = 0; j < 16; ++j) {
    const int h = wv * 16 + j;
    float tot = ldsT[0][h * 64 + lane] + ldsT[1][h * 64 + lane] +
                ldsT[2][h * 64 + lane] + ldsT[3][h * 64 + lane];
    tot += b1[h];
    tot = tot > 0.f ? tot : 0.f;  // relu
    p = fmaf(tot, W2[h], p);
  }
  lds3[wv][lane] = p;
  __syncthreads();
  if (tid < 64) {
    scores[tok0 + tid] =
        lds3[0][tid] + lds3[1][tid] + lds3[2][tid] + lds3[3][tid] + b2[0];
  }
}

// ---------------------------------------------------------------------------
// K2: exact top-k by rank counting. rank(i) = #{j: s_j>s_i} + #{j<i: s_j==s_i}
// reproduces jax.lax.top_k ordering (descending, ties -> lower index first).
// 256 blocks x 256 threads: block = (batch, 64-wide i-chunk); the 4 waves
// split the j-range 4 ways, tree-combined through LDS.
// ---------------------------------------------------------------------------
__global__ __launch_bounds__(256) void k2_topk(
    const float* __restrict__ scores, float* __restrict__ out_idx) {
  __shared__ __align__(16) float sc[SS];
  __shared__ int red[256];
  const int tid = threadIdx.x;
  const int b = blockIdx.x >> 6;
  const int ic = blockIdx.x & 63;
  const float* row = scores + (size_t)b * SS;
#pragma unroll
  for (int q = 0; q < 4; ++q) {
    int f = tid + q * 256;  // float4 index
    *reinterpret_cast<f4*>(&sc[f * 4]) =
        *reinterpret_cast<const f4*>(&row[f * 4]);
  }
  __syncthreads();
  const int il = tid & 63;
  const int part = tid >> 6;  // j quarter (wave-uniform)
  const int i = ic * 64 + il;
  const float si = sc[i];
  const f4* s4 = reinterpret_cast<const f4*>(sc);
  int cnt = 0;
  for (int j4 = part * 256; j4 < part * 256 + 256; ++j4) {
    f4 v = s4[j4];  // broadcast LDS read
    int j = j4 * 4;
    cnt += (int)(v.x > si) + (int)((v.x == si) & (j + 0 < i));
    cnt += (int)(v.y > si) + (int)((v.y == si) & (j + 1 < i));
    cnt += (int)(v.z > si) + (int)((v.z == si) & (j + 2 < i));
    cnt += (int)(v.w > si) + (int)((v.w == si) & (j + 3 < i));
  }
  red[tid] = cnt;
  __syncthreads();
  if (tid < 64) {
    int tot = red[tid] + red[tid + 64] + red[tid + 128] + red[tid + 192];
    if (tot < KTOP) out_idx[b * KTOP + tot] = (float)(ic * 64 + tid);
  }
}

// ---------------------------------------------------------------------------
// K3: attention_pattern[b,i,:] = col_mask[b,:] for all i.
// 1024 blocks x 256 threads; block owns 16 rows of one batch. Nontemporal
// stores (R2/R3/R4 evidence: NT ~17us — L3 absorbs the 268MB stream at
// ~16 TB/s effective; plain stores ~67us via L2 writeback).
// ---------------------------------------------------------------------------
__global__ __launch_bounds__(256) void k3_pattern(
    const float* __restrict__ out_idx, float* __restrict__ pat) {
  __shared__ __align__(16) float mask[SS];
  const int tid = threadIdx.x;
  const int b  = blockIdx.x >> 8;            // 256 blocks per batch
  const int r0 = (blockIdx.x & 255) * 16;
  const f4 zero = (f4){0.f, 0.f, 0.f, 0.f};
#pragma unroll
  for (int q = 0; q < 4; ++q) {
    int f = tid + q * 256;
    *reinterpret_cast<f4*>(&mask[f * 4]) = zero;
  }
  __syncthreads();
  if (tid < KTOP) {
    int c = (int)out_idx[b * KTOP + tid];
    mask[c] = 1.0f / (float)KTOP;
  }
  __syncthreads();
  const f4 m0 = *reinterpret_cast<const f4*>(&mask[(tid)*4]);
  const f4 m1 = *reinterpret_cast<const f4*>(&mask[(tid + 256) * 4]);
  const f4 m2 = *reinterpret_cast<const f4*>(&mask[(tid + 512) * 4]);
  const f4 m3 = *reinterpret_cast<const f4*>(&mask[(tid + 768) * 4]);
  for (int r = 0; r < 16; ++r) {
    f4* p4 = reinterpret_cast<f4*>(pat + ((size_t)b * SS + r0 + r) * SS);
    __builtin_nontemporal_store(m0, &p4[tid]);
    __builtin_nontemporal_store(m1, &p4[tid + 256]);
    __builtin_nontemporal_store(m2, &p4[tid + 512]);
    __builtin_nontemporal_store(m3, &p4[tid + 768]);
  }
}

extern "C" void kernel_launch(void* const* d_in, const int* in_sizes, int n_in,
                              void* d_out, int out_size, void* d_ws,
                              size_t ws_size, hipStream_t stream) {
  const float* emb = (const float*)d_in[0];
  const float* W1  = (const float*)d_in[1];
  const float* b1  = (const float*)d_in[2];
  const float* W2  = (const float*)d_in[3];
  const float* b2  = (const float*)d_in[4];
  float* out = (float*)d_out;
  float* pat     = out;              // [B,S,S] pattern
  float* out_idx = out + PATTERN_N;  // [B,KTOP] indices as float
  // scores scratch lives in the first 64 KB of the pattern region;
  // K3 overwrites it afterwards (kernels are stream-ordered).
  float* scores = out;

  k1_scores<<<dim3((BB * SS) / 64), dim3(256), 0, stream>>>(emb, W1, b1, W2,
                                                            b2, scores);
  k2_topk<<<dim3(BB * (SS / 64)), dim3(256), 0, stream>>>(scores, out_idx);
  k3_pattern<<<dim3((BB * SS) / 16), dim3(256), 0, stream>>>(out_idx, pat);
}

// Round 6
// 172.713 us; speedup vs baseline: 1.3096x; 1.3096x over previous
//
#include <hip/hip_runtime.h>

// Sizes fixed by the reference.
#define BB 4
#define SS 4096
#define DM 1024
#define HID 64
#define KTOP 204
static constexpr size_t PATTERN_N = (size_t)BB * SS * SS;  // 67108864

typedef float f4 __attribute__((ext_vector_type(4)));

// ---------------------------------------------------------------------------
// K1: scores[b,s] = relu(emb[b,s,:] @ W1 + b1) @ W2 + b2
// 512 blocks x 256 threads. lane = token (64/block); wave = 256-wide d-slice,
// processed in 32-d chunks (LDS 34.3KB -> 4 blocks/CU). Per k:
//   1 ds_read_b32 (e[token][k], conflict-free) +
//   W1 row k via SMEM (readfirstlane-forced uniform base -> s_load_dwordx16,
//   K$-resident since all waves walk W1 in lockstep) +
//   64 v_fmac (SGPR w-operand) into acc[64].
// VALU floor = 27.3 us. R5 failure mode (w as 64 per-lane VMEM loads/k,
// VALUBusy 9.5%) is fixed by the forced-uniform scalar path.
// ---------------------------------------------------------------------------
__global__ __launch_bounds__(256, 4) void k1_scores(
    const float* __restrict__ emb, const float* __restrict__ W1,
    const float* __restrict__ b1, const float* __restrict__ W2,
    const float* __restrict__ b2, float* __restrict__ scores) {
  __shared__ __align__(16) float ldsT[4][32 * 65];  // per-wave transpose buf
  __shared__ float lds3[4][64];
  const int tid = threadIdx.x;
  const int lane = tid & 63;  // token within block
  const int wv = tid >> 6;    // d-slice id
  const int tok0 = blockIdx.x * 64;
  const int dsl0 = wv * 256;
  const int c4col = lane >> 3;  // f4-column (0..7) within 32-d chunk
  const int rlane = lane & 7;   // row sub-offset

  float acc[64];
#pragma unroll
  for (int h = 0; h < 64; ++h) acc[h] = 0.f;

  float* __restrict__ Tw = &ldsT[wv][0];

#pragma unroll 1
  for (int ch = 0; ch < 8; ++ch) {
    const int d0 = dsl0 + ch * 32;
    // stage 64 tok x 32 d, transposed [d][tok] stride 65 (wave-local).
    // global: 8 lanes x 16B = 128B contiguous per row -> coalesced.
    // LDS write banks: (4*c4col + rlane) % 32 -> max 2-way (free).
#pragma unroll
    for (int i = 0; i < 8; ++i) {
      const int r = i * 8 + rlane;
      f4 v = *reinterpret_cast<const f4*>(
          &emb[((size_t)tok0 + r) * DM + d0 + c4col * 4]);
      Tw[(c4col * 4 + 0) * 65 + r] = v.x;
      Tw[(c4col * 4 + 1) * 65 + r] = v.y;
      Tw[(c4col * 4 + 2) * 65 + r] = v.z;
      Tw[(c4col * 4 + 3) * 65 + r] = v.w;
    }
    // wave-local write->read ordering (own region only, no barrier needed)
    asm volatile("s_waitcnt lgkmcnt(0)" ::: "memory");
    const float* __restrict__ wbase =
        W1 + (size_t)__builtin_amdgcn_readfirstlane(d0) * HID;
#pragma unroll 2
    for (int k = 0; k < 32; ++k) {
      const float ev = Tw[k * 65 + lane];
      const float* __restrict__ wk = wbase + (size_t)k * HID;
#pragma unroll
      for (int h = 0; h < 64; ++h) acc[h] = fmaf(ev, wk[h], acc[h]);
    }
  }

  // Epilogue in two 32-h phases (buffer = 2080 floats/wave >= 2048).
  float p = 0.f;
#pragma unroll 1
  for (int half = 0; half < 2; ++half) {
#pragma unroll
    for (int j = 0; j < 32; ++j) Tw[j * 64 + lane] = acc[half * 32 + j];
    __syncthreads();
#pragma unroll
    for (int j = 0; j < 8; ++j) {
      const int hh = wv * 8 + j;          // row within buffer
      const int h = half * 32 + hh;       // true hidden index
      float tot = ldsT[0][hh * 64 + lane] + ldsT[1][hh * 64 + lane] +
                  ldsT[2][hh * 64 + lane] + ldsT[3][hh * 64 + lane];
      tot += b1[h];
      tot = tot > 0.f ? tot : 0.f;  // relu
      p = fmaf(tot, W2[h], p);
    }
    __syncthreads();  // all reads done before next phase overwrites
  }
  lds3[wv][lane] = p;
  __syncthreads();
  if (tid < 64) {
    scores[tok0 + tid] =
        lds3[0][tid] + lds3[1][tid] + lds3[2][tid] + lds3[3][tid] + b2[0];
  }
}

// ---------------------------------------------------------------------------
// K2: exact top-k by rank counting. rank(i) = #{j: s_j>s_i} + #{j<i: s_j==s_i}
// reproduces jax.lax.top_k ordering (descending, ties -> lower index first).
// 256 blocks x 256 threads: block = (batch, 64-wide i-chunk); the 4 waves
// split the j-range 4 ways, tree-combined through LDS.
// ---------------------------------------------------------------------------
__global__ __launch_bounds__(256) void k2_topk(
    const float* __restrict__ scores, float* __restrict__ out_idx) {
  __shared__ __align__(16) float sc[SS];
  __shared__ int red[256];
  const int tid = threadIdx.x;
  const int b = blockIdx.x >> 6;
  const int ic = blockIdx.x & 63;
  const float* row = scores + (size_t)b * SS;
#pragma unroll
  for (int q = 0; q < 4; ++q) {
    int f = tid + q * 256;  // float4 index
    *reinterpret_cast<f4*>(&sc[f * 4]) =
        *reinterpret_cast<const f4*>(&row[f * 4]);
  }
  __syncthreads();
  const int il = tid & 63;
  const int part = tid >> 6;  // j quarter (wave-uniform)
  const int i = ic * 64 + il;
  const float si = sc[i];
  const f4* s4 = reinterpret_cast<const f4*>(sc);
  int cnt = 0;
  for (int j4 = part * 256; j4 < part * 256 + 256; ++j4) {
    f4 v = s4[j4];  // broadcast LDS read
    int j = j4 * 4;
    cnt += (int)(v.x > si) + (int)((v.x == si) & (j + 0 < i));
    cnt += (int)(v.y > si) + (int)((v.y == si) & (j + 1 < i));
    cnt += (int)(v.z > si) + (int)((v.z == si) & (j + 2 < i));
    cnt += (int)(v.w > si) + (int)((v.w == si) & (j + 3 < i));
  }
  red[tid] = cnt;
  __syncthreads();
  if (tid < 64) {
    int tot = red[tid] + red[tid + 64] + red[tid + 128] + red[tid + 192];
    if (tot < KTOP) out_idx[b * KTOP + tot] = (float)(ic * 64 + tid);
  }
}

// ---------------------------------------------------------------------------
// K3: attention_pattern[b,i,:] = col_mask[b,:] for all i.
// 1024 blocks x 256 threads; block owns 16 rows of one batch. Nontemporal
// stores (R2/R3/R4 evidence: NT ~17us — L3 absorbs the 268MB stream;
// plain stores ~67us via L2 writeback).
// ---------------------------------------------------------------------------
__global__ __launch_bounds__(256) void k3_pattern(
    const float* __restrict__ out_idx, float* __restrict__ pat) {
  __shared__ __align__(16) float mask[SS];
  const int tid = threadIdx.x;
  const int b  = blockIdx.x >> 8;            // 256 blocks per batch
  const int r0 = (blockIdx.x & 255) * 16;
  const f4 zero = (f4){0.f, 0.f, 0.f, 0.f};
#pragma unroll
  for (int q = 0; q < 4; ++q) {
    int f = tid + q * 256;
    *reinterpret_cast<f4*>(&mask[f * 4]) = zero;
  }
  __syncthreads();
  if (tid < KTOP) {
    int c = (int)out_idx[b * KTOP + tid];
    mask[c] = 1.0f / (float)KTOP;
  }
  __syncthreads();
  const f4 m0 = *reinterpret_cast<const f4*>(&mask[(tid)*4]);
  const f4 m1 = *reinterpret_cast<const f4*>(&mask[(tid + 256) * 4]);
  const f4 m2 = *reinterpret_cast<const f4*>(&mask[(tid + 512) * 4]);
  const f4 m3 = *reinterpret_cast<const f4*>(&mask[(tid + 768) * 4]);
  for (int r = 0; r < 16; ++r) {
    f4* p4 = reinterpret_cast<f4*>(pat + ((size_t)b * SS + r0 + r) * SS);
    __builtin_nontemporal_store(m0, &p4[tid]);
    __builtin_nontemporal_store(m1, &p4[tid + 256]);
    __builtin_nontemporal_store(m2, &p4[tid + 512]);
    __builtin_nontemporal_store(m3, &p4[tid + 768]);
  }
}

extern "C" void kernel_launch(void* const* d_in, const int* in_sizes, int n_in,
                              void* d_out, int out_size, void* d_ws,
                              size_t ws_size, hipStream_t stream) {
  const float* emb = (const float*)d_in[0];
  const float* W1  = (const float*)d_in[1];
  const float* b1  = (const float*)d_in[2];
  const float* W2  = (const float*)d_in[3];
  const float* b2  = (const float*)d_in[4];
  float* out = (float*)d_out;
  float* pat     = out;              // [B,S,S] pattern
  float* out_idx = out + PATTERN_N;  // [B,KTOP] indices as float
  // scores scratch lives in the first 64 KB of the pattern region;
  // K3 overwrites it afterwards (kernels are stream-ordered).
  float* scores = out;

  k1_scores<<<dim3((BB * SS) / 64), dim3(256), 0, stream>>>(emb, W1, b1, W2,
                                                            b2, scores);
  k2_topk<<<dim3(BB * (SS / 64)), dim3(256), 0, stream>>>(scores, out_idx);
  k3_pattern<<<dim3((BB * SS) / 16), dim3(256), 0, stream>>>(out_idx, pat);
}

// Round 7
// 121.539 us; speedup vs baseline: 1.8610x; 1.4211x over previous
//
#include <hip/hip_runtime.h>

// Sizes fixed by the reference.
#define BB 4
#define SS 4096
#define DM 1024
#define HID 64
#define KTOP 204
static constexpr size_t PATTERN_N = (size_t)BB * SS * SS;  // 67108864

typedef float f4 __attribute__((ext_vector_type(4)));
typedef float f32x4 __attribute__((ext_vector_type(4)));
typedef _Float16 h8v __attribute__((ext_vector_type(8)));

// d_out scratch layout (float offsets), all < PATTERN_N, overwritten by K3:
//   [0,      16384) : scores [B*S] f32
//   [16384,  49152) : Wfrag_hi  65536 f16 (pre-swizzled MFMA B-fragments)
//   [49152,  81920) : Wfrag_lo  65536 f16
#define SCORES_OFF 0
#define WHF_OFF 16384
#define WLF_OFF 49152

// ---------------------------------------------------------------------------
// K0: convert W1 (f32 [1024][64]) -> fp16 hi/lo MFMA B-fragments, scaled
// by 1024 so W1 and its lo-residual stay in fp16 normal range.
// Fragment order: frag[(k0*4+nt)*64 + lane][j], j=0..7, where the lane
// holds W[k0*32 + 8*(lane>>4) + j][nt*16 + (lane&15)]  (B: col=lane&15,
// k=8*(lane>>4)+j for mfma_f32_16x16x32_f16).
// ---------------------------------------------------------------------------
__global__ __launch_bounds__(256) void k0_wconv(
    const float* __restrict__ W1, _Float16* __restrict__ whf,
    _Float16* __restrict__ wlf) {
  const int gid = blockIdx.x * 256 + threadIdx.x;  // 8192 total
  const int l = gid & 63;
  const int nt = (gid >> 6) & 3;
  const int k0 = gid >> 8;  // 0..31
  const int kb = k0 * 32 + (l >> 4) * 8;
  const int n = nt * 16 + (l & 15);
  h8v hi, lo;
#pragma unroll
  for (int j = 0; j < 8; ++j) {
    float w = W1[(size_t)(kb + j) * HID + n] * 1024.f;
    _Float16 h = (_Float16)w;
    hi[j] = h;
    lo[j] = (_Float16)((w - (float)h) * 4096.f);
  }
  reinterpret_cast<h8v*>(whf)[(k0 * 4 + nt) * 64 + l] = hi;
  reinterpret_cast<h8v*>(wlf)[(k0 * 4 + nt) * 64 + l] = lo;
}

// ---------------------------------------------------------------------------
// K1: scores = relu(emb @ W1 + b1) @ W2 + b2 via fp16x3 MFMA emulation of
// fp32:  e = eh + 2^-12*el;  e@W1*1024 = Ah@Wh + 2^-12*(Al@Wh + Ah@Wl).
// 256 blocks x 256 thr; wave owns 32 tokens (2 M-tiles) x 64 hidden
// (4 N-tiles), K=1024 in 32 steps. A-frags straight from global (16 rows x
// 128B per load instr -> line-coalesced), converted in-register. B-frags
// from the K0-swizzled table (L2-resident). No LDS, no barriers.
// C/D layout (m89-verified): col=lane&15, row=(lane>>4)*4+i.
// ---------------------------------------------------------------------------
__global__ __launch_bounds__(256) void k1_mfma(
    const float* __restrict__ emb, const _Float16* __restrict__ whf,
    const _Float16* __restrict__ wlf, const float* __restrict__ b1,
    const float* __restrict__ W2, const float* __restrict__ b2,
    float* __restrict__ scores) {
  const int tid = threadIdx.x;
  const int l = tid & 63;
  const int wv = tid >> 6;
  const int tokw = blockIdx.x * 128 + wv * 32;  // wave's 32 tokens
  const int lrow = l & 15;
  const int lk8 = (l >> 4) * 8;

  const float* __restrict__ ap0 = emb + (size_t)(tokw + lrow) * DM + lk8;
  const float* __restrict__ ap1 = emb + (size_t)(tokw + 16 + lrow) * DM + lk8;
  const h8v* __restrict__ bhp = reinterpret_cast<const h8v*>(whf);
  const h8v* __restrict__ blp = reinterpret_cast<const h8v*>(wlf);

  f32x4 acc0[2][4], acc1[2][4];
#pragma unroll
  for (int mt = 0; mt < 2; ++mt)
#pragma unroll
    for (int nt = 0; nt < 4; ++nt) {
      acc0[mt][nt] = (f32x4){0.f, 0.f, 0.f, 0.f};
      acc1[mt][nt] = (f32x4){0.f, 0.f, 0.f, 0.f};
    }

  // current-step raw A (8 f32 per m-tile) and B frags
  f4 a0c, a1c, a0c2, a1c2;
  h8v bhc[4], blc[4];
  a0c = *reinterpret_cast<const f4*>(ap0);
  a0c2 = *reinterpret_cast<const f4*>(ap0 + 4);
  a1c = *reinterpret_cast<const f4*>(ap1);
  a1c2 = *reinterpret_cast<const f4*>(ap1 + 4);
#pragma unroll
  for (int nt = 0; nt < 4; ++nt) {
    bhc[nt] = bhp[nt * 64 + l];
    blc[nt] = blp[nt * 64 + l];
  }

#pragma unroll 2
  for (int k0 = 0; k0 < 32; ++k0) {
    f4 a0n, a1n, a0n2, a1n2;
    h8v bhn[4], bln[4];
    if (k0 < 31) {  // prefetch next K-step
      const int koff = (k0 + 1) * 32;
      a0n = *reinterpret_cast<const f4*>(ap0 + koff);
      a0n2 = *reinterpret_cast<const f4*>(ap0 + koff + 4);
      a1n = *reinterpret_cast<const f4*>(ap1 + koff);
      a1n2 = *reinterpret_cast<const f4*>(ap1 + koff + 4);
#pragma unroll
      for (int nt = 0; nt < 4; ++nt) {
        bhn[nt] = bhp[((k0 + 1) * 4 + nt) * 64 + l];
        bln[nt] = blp[((k0 + 1) * 4 + nt) * 64 + l];
      }
    }
    // convert current A to fp16 hi/lo fragments
    h8v ah[2], al[2];
#pragma unroll
    for (int j = 0; j < 4; ++j) {
      _Float16 h;
      h = (_Float16)a0c[j];  ah[0][j] = h;
      al[0][j] = (_Float16)((a0c[j] - (float)h) * 4096.f);
      h = (_Float16)a0c2[j]; ah[0][4 + j] = h;
      al[0][4 + j] = (_Float16)((a0c2[j] - (float)h) * 4096.f);
      h = (_Float16)a1c[j];  ah[1][j] = h;
      al[1][j] = (_Float16)((a1c[j] - (float)h) * 4096.f);
      h = (_Float16)a1c2[j]; ah[1][4 + j] = h;
      al[1][4 + j] = (_Float16)((a1c2[j] - (float)h) * 4096.f);
    }
#pragma unroll
    for (int mt = 0; mt < 2; ++mt)
#pragma unroll
      for (int nt = 0; nt < 4; ++nt) {
        acc0[mt][nt] = __builtin_amdgcn_mfma_f32_16x16x32_f16(
            ah[mt], bhc[nt], acc0[mt][nt], 0, 0, 0);
        acc1[mt][nt] = __builtin_amdgcn_mfma_f32_16x16x32_f16(
            al[mt], bhc[nt], acc1[mt][nt], 0, 0, 0);
        acc1[mt][nt] = __builtin_amdgcn_mfma_f32_16x16x32_f16(
            ah[mt], blc[nt], acc1[mt][nt], 0, 0, 0);
      }
    if (k0 < 31) {  // rotate
      a0c = a0n; a0c2 = a0n2; a1c = a1n; a1c2 = a1n2;
#pragma unroll
      for (int nt = 0; nt < 4; ++nt) { bhc[nt] = bhn[nt]; blc[nt] = bln[nt]; }
    }
  }

  // Epilogue: h = relu((acc0 + 2^-12 acc1)*2^-10 + b1); p = h @ W2; reduce
  // across the 16 cols held by lanes sharing (l>>4); + b2.
  float w2v[4], b1v[4];
#pragma unroll
  for (int nt = 0; nt < 4; ++nt) {
    w2v[nt] = W2[nt * 16 + lrow];
    b1v[nt] = b1[nt * 16 + lrow];
  }
  const float bb2 = b2[0];
#pragma unroll
  for (int mt = 0; mt < 2; ++mt)
#pragma unroll
    for (int i = 0; i < 4; ++i) {
      float p = 0.f;
#pragma unroll
      for (int nt = 0; nt < 4; ++nt) {
        float hs = (acc0[mt][nt][i] + 0x1p-12f * acc1[mt][nt][i]) * 0x1p-10f +
                   b1v[nt];
        hs = hs > 0.f ? hs : 0.f;
        p = fmaf(hs, w2v[nt], p);
      }
      p += __shfl_xor(p, 1, 64);
      p += __shfl_xor(p, 2, 64);
      p += __shfl_xor(p, 4, 64);
      p += __shfl_xor(p, 8, 64);
      if (lrow == 0)
        scores[tokw + mt * 16 + (l >> 4) * 4 + i] = p + bb2;
    }
}

// ---------------------------------------------------------------------------
// K2: exact top-k by rank counting. rank(i) = #{j: s_j>s_i} + #{j<i: s_j==s_i}
// reproduces jax.lax.top_k ordering (descending, ties -> lower index first).
// 256 blocks x 256 threads: block = (batch, 64-wide i-chunk); the 4 waves
// split the j-range 4 ways, tree-combined through LDS.
// ---------------------------------------------------------------------------
__global__ __launch_bounds__(256) void k2_topk(
    const float* __restrict__ scores, float* __restrict__ out_idx) {
  __shared__ __align__(16) float sc[SS];
  __shared__ int red[256];
  const int tid = threadIdx.x;
  const int b = blockIdx.x >> 6;
  const int ic = blockIdx.x & 63;
  const float* row = scores + (size_t)b * SS;
#pragma unroll
  for (int q = 0; q < 4; ++q) {
    int f = tid + q * 256;  // float4 index
    *reinterpret_cast<f4*>(&sc[f * 4]) =
        *reinterpret_cast<const f4*>(&row[f * 4]);
  }
  __syncthreads();
  const int il = tid & 63;
  const int part = tid >> 6;  // j quarter (wave-uniform)
  const int i = ic * 64 + il;
  const float si = sc[i];
  const f4* s4 = reinterpret_cast<const f4*>(sc);
  int cnt = 0;
  for (int j4 = part * 256; j4 < part * 256 + 256; ++j4) {
    f4 v = s4[j4];  // broadcast LDS read
    int j = j4 * 4;
    cnt += (int)(v.x > si) + (int)((v.x == si) & (j + 0 < i));
    cnt += (int)(v.y > si) + (int)((v.y == si) & (j + 1 < i));
    cnt += (int)(v.z > si) + (int)((v.z == si) & (j + 2 < i));
    cnt += (int)(v.w > si) + (int)((v.w == si) & (j + 3 < i));
  }
  red[tid] = cnt;
  __syncthreads();
  if (tid < 64) {
    int tot = red[tid] + red[tid + 64] + red[tid + 128] + red[tid + 192];
    if (tot < KTOP) out_idx[b * KTOP + tot] = (float)(ic * 64 + tid);
  }
}

// ---------------------------------------------------------------------------
// K3: attention_pattern[b,i,:] = col_mask[b,:] for all i.
// 1024 blocks x 256 threads; block owns 16 rows of one batch. Nontemporal
// stores (R2/R3 A/B: NT ~17us, plain ~67us for the 268MB stream).
// ---------------------------------------------------------------------------
__global__ __launch_bounds__(256) void k3_pattern(
    const float* __restrict__ out_idx, float* __restrict__ pat) {
  __shared__ __align__(16) float mask[SS];
  const int tid = threadIdx.x;
  const int b  = blockIdx.x >> 8;            // 256 blocks per batch
  const int r0 = (blockIdx.x & 255) * 16;
  const f4 zero = (f4){0.f, 0.f, 0.f, 0.f};
#pragma unroll
  for (int q = 0; q < 4; ++q) {
    int f = tid + q * 256;
    *reinterpret_cast<f4*>(&mask[f * 4]) = zero;
  }
  __syncthreads();
  if (tid < KTOP) {
    int c = (int)out_idx[b * KTOP + tid];
    mask[c] = 1.0f / (float)KTOP;
  }
  __syncthreads();
  const f4 m0 = *reinterpret_cast<const f4*>(&mask[(tid)*4]);
  const f4 m1 = *reinterpret_cast<const f4*>(&mask[(tid + 256) * 4]);
  const f4 m2 = *reinterpret_cast<const f4*>(&mask[(tid + 512) * 4]);
  const f4 m3 = *reinterpret_cast<const f4*>(&mask[(tid + 768) * 4]);
  for (int r = 0; r < 16; ++r) {
    f4* p4 = reinterpret_cast<f4*>(pat + ((size_t)b * SS + r0 + r) * SS);
    __builtin_nontemporal_store(m0, &p4[tid]);
    __builtin_nontemporal_store(m1, &p4[tid + 256]);
    __builtin_nontemporal_store(m2, &p4[tid + 512]);
    __builtin_nontemporal_store(m3, &p4[tid + 768]);
  }
}

extern "C" void kernel_launch(void* const* d_in, const int* in_sizes, int n_in,
                              void* d_out, int out_size, void* d_ws,
                              size_t ws_size, hipStream_t stream) {
  const float* emb = (const float*)d_in[0];
  const float* W1  = (const float*)d_in[1];
  const float* b1  = (const float*)d_in[2];
  const float* W2  = (const float*)d_in[3];
  const float* b2  = (const float*)d_in[4];
  float* out = (float*)d_out;
  float* pat     = out;              // [B,S,S] pattern
  float* out_idx = out + PATTERN_N;  // [B,KTOP] indices as float
  float* scores = out + SCORES_OFF;
  _Float16* whf = (_Float16*)(out + WHF_OFF);
  _Float16* wlf = (_Float16*)(out + WLF_OFF);

  k0_wconv<<<dim3(32), dim3(256), 0, stream>>>(W1, whf, wlf);
  k1_mfma<<<dim3((BB * SS) / 128), dim3(256), 0, stream>>>(emb, whf, wlf, b1,
                                                           W2, b2, scores);
  k2_topk<<<dim3(BB * (SS / 64)), dim3(256), 0, stream>>>(scores, out_idx);
  k3_pattern<<<dim3((BB * SS) / 16), dim3(256), 0, stream>>>(out_idx, pat);
}